// Round 7
// baseline (122.776 us; speedup 1.0000x reference)
//
#include <hip/hip_runtime.h>
#include <stdint.h>

#define SEQ   2048
#define DEMB  1024
#define NH    16
#define HD    64
#define MROWS 4096   // BS*SEQ

typedef __bf16 bf16x8 __attribute__((ext_vector_type(8)));
typedef __bf16 bf16x4 __attribute__((ext_vector_type(4)));
typedef float  f32x4  __attribute__((ext_vector_type(4)));

#define MFMA(a, b, c) __builtin_amdgcn_mfma_f32_16x16x32_bf16((a), (b), (c), 0, 0, 0)

static __device__ __forceinline__ uint16_t f2bf(float f) {
  union { __bf16 b; uint16_t u; } c;
  c.b = (__bf16)f;
  return c.u;
}

static __device__ __forceinline__ ushort4 pack4(f32x4 f) {
  union { bf16x4 b; ushort4 u; } c;
  c.b[0] = (__bf16)f[0]; c.b[1] = (__bf16)f[1];
  c.b[2] = (__bf16)f[2]; c.b[3] = (__bf16)f[3];
  return c.u;
}

static __device__ __forceinline__ bf16x8 ldb8(const uint16_t* p) {
  union { uint4 i; bf16x8 b; } u;
  u.i = *(const uint4*)p;
  return u.b;
}

static __device__ __forceinline__ void gld_lds16(const uint16_t* g, uint16_t* l) {
  __builtin_amdgcn_global_load_lds(
      (const __attribute__((address_space(1))) uint32_t*)(g),
      (__attribute__((address_space(3))) uint32_t*)(l),
      16, 0, 0);
}

// ---------------------------------------------------------------- fused converts
__global__ __launch_bounds__(256) void cvt_all(const float* __restrict__ x,
                                               const float* __restrict__ wq,
                                               const float* __restrict__ wk,
                                               const float* __restrict__ wv,
                                               const float* __restrict__ wo,
                                               uint16_t* __restrict__ xb,
                                               uint16_t* __restrict__ wqkv,
                                               uint16_t* __restrict__ wob) {
  const int bid = blockIdx.x;
  const float* src; uint16_t* dst; int off;
  if (bid < 4096)      { src = x;  dst = xb;                 off = bid; }
  else if (bid < 5120) { src = wq; dst = wqkv;               off = bid - 4096; }
  else if (bid < 6144) { src = wk; dst = wqkv + (1u << 20);  off = bid - 5120; }
  else if (bid < 7168) { src = wv; dst = wqkv + (2u << 20);  off = bid - 6144; }
  else                 { src = wo; dst = wob;                off = bid - 7168; }
  const int i = (off * 256 + threadIdx.x) * 4;
  float4 v = *(const float4*)(src + i);
  f32x4 f; f[0] = v.x; f[1] = v.y; f[2] = v.z; f[3] = v.w;
  *(ushort4*)(dst + i) = pack4(f);
}

// ---------------------------------------------------------------- GEMM C = A * B^T
// BM=128, BK=64 (128-B LDS rows -> conflict-free swizzle, R5-validated),
// 512 threads (8 waves, 2M x 4N), double-buffered, 16 K-steps, XCD-swizzled grid.
// MODE 0: BN=128, fused QKV epilogue (N=3072, nbx=24): [0,1024)->Q (*log2e/8),
//         [1024,2048)->K, [2048,3072)->V^T per head (b,h,d,s).
// MODE 2: BN=64 (nbx=16), fp32 out + bias.
template <int MODE>
__global__ __launch_bounds__(512) void gemm_bt(const uint16_t* __restrict__ A,
                                               const uint16_t* __restrict__ B,
                                               uint16_t* __restrict__ Cq,
                                               uint16_t* __restrict__ Ck,
                                               uint16_t* __restrict__ Cvt,
                                               float* __restrict__ Cf,
                                               const float* __restrict__ bias) {
  constexpr int K   = 1024;
  constexpr int BN  = (MODE == 0) ? 128 : 64;
  constexpr int NI  = (MODE == 0) ? 2 : 1;     // per-wave N fragments
  constexpr int NBX = (MODE == 0) ? 24 : 16;
  constexpr int CHUNK = (MODE == 0) ? 96 : 64; // nwg/8, both nwg%8==0

  __shared__ uint16_t As[2][128 * 64];
  __shared__ uint16_t Bs[2][BN * 64];

  // bijective XCD swizzle: consecutive per-XCD ranks share the A row-panel
  const int id  = blockIdx.x;
  const int swz = (id & 7) * CHUNK + (id >> 3);
  const int brow = (swz / NBX) << 7;
  const int bcol = (swz % NBX) * BN;

  const int t  = threadIdx.x;
  const int l  = t & 63;
  const int li = l & 15, lg = l >> 4;
  const int w  = t >> 6;               // 0..7
  const int wm = w >> 2;               // rows wm*64
  const int wn = w & 3;                // cols wn*(BN/4)

  // staging: thread t -> row t>>3 (0..63), 16B-slot t&7; source col pre-swizzled
  // by (row&7) so linear LDS + XOR reads are conflict-free (0 conflicts, R5).
  const int srow = t >> 3;
  const int scol = ((t & 7) ^ (srow & 7)) << 3;
  const uint16_t* gA = A + (size_t)(brow + srow) * K + scol;
  const uint16_t* gB = B + (size_t)(bcol + srow) * K + scol;

  auto stage = [&](int buf, int k0) {
    gld_lds16(gA + k0, &As[buf][t * 8]);
    gld_lds16(gA + (size_t)64 * K + k0, &As[buf][4096 + t * 8]);
    gld_lds16(gB + k0, &Bs[buf][t * 8]);
    if (MODE == 0) gld_lds16(gB + (size_t)64 * K + k0, &Bs[buf][4096 + t * 8]);
  };

  const int sw = li & 7;               // fragment-read swizzle
  auto ldA = [&](int buf, int kh, int fi) {
    const int row = wm * 64 + fi * 16 + li;
    return ldb8(&As[buf][(row << 6) + ((((kh << 2) + lg) ^ sw) << 3)]);
  };
  auto ldB = [&](int buf, int kh, int ni) {
    const int row = wn * (BN / 4) + ni * 16 + li;
    return ldb8(&Bs[buf][(row << 6) + ((((kh << 2) + lg) ^ sw) << 3)]);
  };

  f32x4 acc[4][NI] = {};

  stage(0, 0);
  __syncthreads();
  int cur = 0;

  for (int k0 = 0; k0 < K; k0 += 64) {
    if (k0 + 64 < K) stage(cur ^ 1, k0 + 64);   // in flight during compute

#pragma unroll
    for (int kh = 0; kh < 2; ++kh) {
      bf16x8 af[4], bfr[NI];
#pragma unroll
      for (int fi = 0; fi < 4; ++fi) af[fi] = ldA(cur, kh, fi);
#pragma unroll
      for (int ni = 0; ni < NI; ++ni) bfr[ni] = ldB(cur, kh, ni);
      __builtin_amdgcn_s_setprio(1);
#pragma unroll
      for (int fi = 0; fi < 4; ++fi)
#pragma unroll
        for (int ni = 0; ni < NI; ++ni)
          acc[fi][ni] = MFMA(af[fi], bfr[ni], acc[fi][ni]);
      __builtin_amdgcn_s_setprio(0);
    }

    __syncthreads();   // drains staging vmcnt + protects buffer reuse
    cur ^= 1;
  }

#pragma unroll
  for (int mi = 0; mi < 4; ++mi) {
#pragma unroll
    for (int ni = 0; ni < NI; ++ni) {
      const int row = brow + wm * 64 + mi * 16 + lg * 4;   // + r
      const int col = bcol + wn * (BN / 4) + ni * 16 + li;
#pragma unroll
      for (int r = 0; r < 4; ++r) {
        const float v = acc[mi][ni][r];
        if (MODE == 0) {
          if (col < 1024) {
            // Q scaled by 1/sqrt(64) * log2(e) for exp2-domain softmax
            Cq[(size_t)(row + r) * 1024 + col] = f2bf(v * 0.18033688f);
          } else if (col < 2048) {
            Ck[(size_t)(row + r) * 1024 + (col - 1024)] = f2bf(v);
          } else {
            const int c = col - 2048;                 // h*64 + d
            const int m = row + r;                    // b*2048 + s
            Cvt[((size_t)c + (size_t)((m >> 11) << 10)) * 2048 + (m & 2047)] = f2bf(v);
          }
        } else {
          Cf[(size_t)(row + r) * 1024 + col] = v + bias[col];
        }
      }
    }
  }
}

// ---------------------------------------------------------------- flash attention
// 8-wave blocks (512 thr), QBLK=128 (16 q-rows/wave), KVBLK=64.
// One cooperative K/V stage serves 8 waves -> staging traffic & barriers per
// unit work halved vs 4-wave; 2 blocks/CU = 16 waves/CU.
// Swapped-operand no-max softmax (exp2 domain, Q pre-scaled by log2e/8).
// Grid 512 1-D; XCD-aware map: 4 heads per XCD (2MB K/V fits 4MB L2).
__global__ __launch_bounds__(512) void attn_fwd(const uint16_t* __restrict__ Q,
                                                const uint16_t* __restrict__ K,
                                                const uint16_t* __restrict__ Vt,
                                                uint16_t* __restrict__ ctx) {
  const int id   = blockIdx.x;
  const int rank = id >> 3;                  // 0..63
  const int bh   = (id & 7) * 4 + (rank >> 4);
  const int qbl  = 15 - (rank & 15);         // heavy q-blocks first per XCD
  const int b = bh >> 4, h = bh & 15;

  const int t  = threadIdx.x;
  const int w  = t >> 6, l = t & 63;
  const int li = l & 15, lg = l >> 4;

  __shared__ uint16_t Kl[2][64 * 64];   // 8KB x2 (key, d), swizzled
  __shared__ uint16_t Vl[2][64 * 64];   // 8KB x2 (d, key), swizzled
  __shared__ uint16_t P[8][16][72];     // per-wave P slab (144-B rows, aligned)

  const uint16_t* Kg = K + (size_t)(b * 2048) * 1024 + h * 64;
  const uint16_t* Vg = Vt + (size_t)(b * 1024 + h * 64) * 2048;

  // staging: thread t -> row t>>3 (0..63), slot t&7; one call per tile each
  const int srow = t >> 3;
  const int scol = ((t & 7) * 8) ^ ((srow & 7) * 8);

  const int qrow = (qbl << 7) + (w << 4);    // within seq
  const uint16_t* qp = Q + (size_t)(b * 2048 + qrow + li) * 1024 + h * 64 + lg * 8;
  const bf16x8 q0 = ldb8(qp);
  const bf16x8 q1 = ldb8(qp + 32);

  f32x4 o[4] = {};                     // O[d = dt*16 + lg*4 + r][q = li]
  float l_r = 0.f;                     // per-lane partial sum

  auto stage = [&](int buf, int kt2) {
    const int kb2 = kt2 << 6;
    gld_lds16(Kg + (size_t)(kb2 + srow) * 1024 + scol, &Kl[buf][t * 8]);
    gld_lds16(Vg + (size_t)srow * 2048 + kb2 + scol,   &Vl[buf][t * 8]);
  };

  stage(0, 0);
  __syncthreads();
  int cur = 0;

  const int fsw = (li & 7) * 8;
  const int nkt = (qbl << 1) + 2;      // K-tiles covering q-rows (causal)
  const int qglob = qrow + li;         // this lane's q row (global within seq)

  for (int kt = 0; kt < nkt; ++kt) {
    if (kt < nkt - 1) stage(cur ^ 1, kt + 1);

    const uint16_t* Kc = &Kl[cur][0];
    const uint16_t* Vc = &Vl[cur][0];

    // QK^T swapped: s[tt][r] = S[key = kt*64+tt*16+lg*4+r][q = qglob]
    f32x4 s[4];
    __builtin_amdgcn_s_setprio(1);
#pragma unroll
    for (int tt = 0; tt < 4; ++tt) {
      const uint16_t* kr = Kc + (tt * 16 + li) * 64;
      f32x4 z = {};
      z = MFMA(ldb8(kr + ((lg * 8) ^ fsw)), q0, z);
      z = MFMA(ldb8(kr + ((32 + lg * 8) ^ fsw)), q1, z);
      s[tt] = z;
    }
    __builtin_amdgcn_s_setprio(0);

    // V fragments: lane holds V[d = dt*16 + li][key = half*32 + lg*8 + j]
    bf16x8 vf[4][2];
#pragma unroll
    for (int dt = 0; dt < 4; ++dt) {
      const uint16_t* vr = Vc + (dt * 16 + li) * 64;
      vf[dt][0] = ldb8(vr + ((lg * 8) ^ fsw));
      vf[dt][1] = ldb8(vr + ((32 + lg * 8) ^ fsw));
    }

    if ((kt << 6) + 63 > qrow) {       // tile can cross the diagonal: mask
      const int kb = kt << 6;
#pragma unroll
      for (int tt = 0; tt < 4; ++tt) {
        const int key = kb + (tt << 4) + (lg << 2);
#pragma unroll
        for (int r = 0; r < 4; ++r)
          if (key + r > qglob) s[tt][r] = -1e30f;
      }
    }

    // ---- no-max softmax: P = exp2(s), per-lane partial l
    float lsum = 0.f;
    ushort4 pk[4];
#pragma unroll
    for (int tt = 0; tt < 4; ++tt) {
      f32x4 p;
      p[0] = __builtin_amdgcn_exp2f(s[tt][0]);
      p[1] = __builtin_amdgcn_exp2f(s[tt][1]);
      p[2] = __builtin_amdgcn_exp2f(s[tt][2]);
      p[3] = __builtin_amdgcn_exp2f(s[tt][3]);
      lsum += (p[0] + p[1]) + (p[2] + p[3]);
      pk[tt] = pack4(p);
    }
    l_r += lsum;

    // ---- P relayout via per-wave LDS slab
#pragma unroll
    for (int tt = 0; tt < 4; ++tt)
      *(ushort4*)&P[w][li][(tt << 4) + (lg << 2)] = pk[tt];
    asm volatile("s_waitcnt lgkmcnt(0)" ::: "memory");

    const bf16x8 pb0 = ldb8(&P[w][li][lg * 8]);
    const bf16x8 pb1 = ldb8(&P[w][li][32 + lg * 8]);
    __builtin_amdgcn_s_setprio(1);
#pragma unroll
    for (int dt = 0; dt < 4; ++dt) {
      o[dt] = MFMA(vf[dt][0], pb0, o[dt]);
      o[dt] = MFMA(vf[dt][1], pb1, o[dt]);
    }
    __builtin_amdgcn_s_setprio(0);

    __syncthreads();
    cur ^= 1;
  }

  // final l reduce across the 4 lg-groups sharing q = li
  l_r += __shfl_xor(l_r, 16);
  l_r += __shfl_xor(l_r, 32);
  const float inv = 1.0f / l_r;
  const int qg = b * 2048 + qrow + li;
#pragma unroll
  for (int dt = 0; dt < 4; ++dt) {
    f32x4 ov = o[dt];
    ov[0] *= inv; ov[1] *= inv; ov[2] *= inv; ov[3] *= inv;
    *(ushort4*)(ctx + (size_t)qg * 1024 + h * 64 + (dt << 4) + (lg << 2)) = pack4(ov);
  }
}

// ---------------------------------------------------------------- launch
extern "C" void kernel_launch(void* const* d_in, const int* in_sizes, int n_in,
                              void* d_out, int out_size, void* d_ws, size_t ws_size,
                              hipStream_t stream) {
  const float* x  = (const float*)d_in[0];
  const float* Wq = (const float*)d_in[1];
  const float* Wk = (const float*)d_in[2];
  const float* Wv = (const float*)d_in[3];
  const float* Wo = (const float*)d_in[4];
  const float* bo = (const float*)d_in[5];
  float* out = (float*)d_out;

  char* ws = (char*)d_ws;
  uint16_t* xb   = (uint16_t*)(ws);                 // 8MB (dead after QKV gemm)
  uint16_t* Wqkv = (uint16_t*)(ws + ( 8u << 20));   // 6MB: Wq|Wk|Wv contiguous
  uint16_t* Wob  = (uint16_t*)(ws + (14u << 20));   // 2MB
  uint16_t* Qb   = (uint16_t*)(ws + (16u << 20));   // 8MB
  uint16_t* Kb   = (uint16_t*)(ws + (24u << 20));   // 8MB
  uint16_t* Vt   = (uint16_t*)(ws + (32u << 20));   // 8MB
  uint16_t* Ctx  = (uint16_t*)(ws);                 // overlays xb

  cvt_all<<<8192, 256, 0, stream>>>(x, Wq, Wk, Wv, Wo, xb, Wqkv, Wob);

  // fused QKV projection: 128x128 tiles, 512 thr, 768 blocks (XCD-swizzled)
  gemm_bt<0><<<768, 512, 0, stream>>>(xb, Wqkv, Qb, Kb, Vt, nullptr, nullptr);

  // attention: 512 blocks (XCD-mapped), 8 waves, QBLK=128
  attn_fwd<<<512, 512, 0, stream>>>(Qb, Kb, Vt, Ctx);

  // output projection + bias: 128x64 tiles, 512 thr, 512 blocks
  gemm_bt<2><<<512, 512, 0, stream>>>(Ctx, Wob, nullptr, nullptr, nullptr, out, bo);
}

// Round 8
// 108.952 us; speedup vs baseline: 1.1269x; 1.1269x over previous
//
#include <hip/hip_runtime.h>
#include <stdint.h>

#define SEQ   2048
#define DEMB  1024
#define NH    16
#define HD    64
#define MROWS 4096   // BS*SEQ

typedef __bf16 bf16x8 __attribute__((ext_vector_type(8)));
typedef __bf16 bf16x4 __attribute__((ext_vector_type(4)));
typedef float  f32x4  __attribute__((ext_vector_type(4)));

#define MFMA(a, b, c) __builtin_amdgcn_mfma_f32_16x16x32_bf16((a), (b), (c), 0, 0, 0)

static __device__ __forceinline__ uint16_t f2bf(float f) {
  union { __bf16 b; uint16_t u; } c;
  c.b = (__bf16)f;
  return c.u;
}

static __device__ __forceinline__ ushort4 pack4(f32x4 f) {
  union { bf16x4 b; ushort4 u; } c;
  c.b[0] = (__bf16)f[0]; c.b[1] = (__bf16)f[1];
  c.b[2] = (__bf16)f[2]; c.b[3] = (__bf16)f[3];
  return c.u;
}

static __device__ __forceinline__ bf16x8 ldb8(const uint16_t* p) {
  union { uint4 i; bf16x8 b; } u;
  u.i = *(const uint4*)p;
  return u.b;
}

static __device__ __forceinline__ void gld_lds16(const uint16_t* g, uint16_t* l) {
  __builtin_amdgcn_global_load_lds(
      (const __attribute__((address_space(1))) uint32_t*)(g),
      (__attribute__((address_space(3))) uint32_t*)(l),
      16, 0, 0);
}

// ---------------------------------------------------------------- fused converts
__global__ __launch_bounds__(256) void cvt_all(const float* __restrict__ x,
                                               const float* __restrict__ wq,
                                               const float* __restrict__ wk,
                                               const float* __restrict__ wv,
                                               const float* __restrict__ wo,
                                               uint16_t* __restrict__ xb,
                                               uint16_t* __restrict__ wqkv,
                                               uint16_t* __restrict__ wob) {
  const int bid = blockIdx.x;
  const float* src; uint16_t* dst; int off;
  if (bid < 4096)      { src = x;  dst = xb;                 off = bid; }
  else if (bid < 5120) { src = wq; dst = wqkv;               off = bid - 4096; }
  else if (bid < 6144) { src = wk; dst = wqkv + (1u << 20);  off = bid - 5120; }
  else if (bid < 7168) { src = wv; dst = wqkv + (2u << 20);  off = bid - 6144; }
  else                 { src = wo; dst = wob;                off = bid - 7168; }
  const int i = (off * 256 + threadIdx.x) * 4;
  float4 v = *(const float4*)(src + i);
  f32x4 f; f[0] = v.x; f[1] = v.y; f[2] = v.z; f[3] = v.w;
  *(ushort4*)(dst + i) = pack4(f);
}

// ---------------------------------------------------------------- GEMM C = A * B^T
// BM=128, BK=64 (128-B LDS rows -> conflict-free swizzle, R5/R7-validated: 0
// conflicts), 512 thr (8 waves, 2M x 4N), double-buffered, 16 K-steps.
// DEFAULT x-major dispatch (no manual XCD swizzle): per-XCD B working set
// stays ~2 panels -> L2-resident (R7 lesson: manual swizzle streamed B, +50% FETCH).
// MODE 0: BN=192 (grid 16x32 = 512 blocks = exactly 2/CU, no tail), fused QKV
//         epilogue: [0,1024)->Q (*log2e/8), [1024,2048)->K, [2048,3072)->V^T.
// MODE 2: BN=64 (grid 16x32, 3/CU capacity), fp32 out + bias.
template <int MODE>
__global__ __launch_bounds__(512, 4) void gemm_bt(const uint16_t* __restrict__ A,
                                                  const uint16_t* __restrict__ B,
                                                  uint16_t* __restrict__ Cq,
                                                  uint16_t* __restrict__ Ck,
                                                  uint16_t* __restrict__ Cvt,
                                                  float* __restrict__ Cf,
                                                  const float* __restrict__ bias) {
  constexpr int K  = 1024;
  constexpr int BN = (MODE == 0) ? 192 : 64;
  constexpr int NI = (MODE == 0) ? 3 : 1;      // per-wave N fragments (x16 cols)

  __shared__ uint16_t As[2][128 * 64];         // 32 KB
  __shared__ uint16_t Bs[2][BN * 64];          // 48 / 16 KB

  const int brow = blockIdx.y << 7;
  const int bcol = blockIdx.x * BN;

  const int t  = threadIdx.x;
  const int l  = t & 63;
  const int li = l & 15, lg = l >> 4;
  const int w  = t >> 6;               // 0..7
  const int wm = w >> 2;               // row half: wm*64
  const int wn = w & 3;                // col quarter: wn*(BN/4)

  // staging: thread t -> row t>>3 (0..63), 16B-slot t&7; source col pre-swizzled
  // by (row&7); linear LDS dest + XOR reads = 0 bank conflicts (measured R5/R7).
  const int srow = t >> 3;
  const int scol = ((t & 7) ^ (srow & 7)) << 3;
  const uint16_t* gA = A + (size_t)(brow + srow) * K + scol;
  const uint16_t* gB = B + (size_t)(bcol + srow) * K + scol;

  auto stage = [&](int buf, int k0) {
    gld_lds16(gA + k0, &As[buf][t * 8]);
    gld_lds16(gA + (size_t)64 * K + k0, &As[buf][4096 + t * 8]);
    gld_lds16(gB + k0, &Bs[buf][t * 8]);
    if (MODE == 0) {
      gld_lds16(gB + (size_t)64 * K + k0,  &Bs[buf][4096 + t * 8]);
      gld_lds16(gB + (size_t)128 * K + k0, &Bs[buf][8192 + t * 8]);
    }
  };

  const int sw = li & 7;               // fragment-read swizzle
  auto ldA = [&](int buf, int kh, int fi) {
    const int row = wm * 64 + fi * 16 + li;
    return ldb8(&As[buf][(row << 6) + ((((kh << 2) + lg) ^ sw) << 3)]);
  };
  auto ldB = [&](int buf, int kh, int ni) {
    const int row = wn * (BN / 4) + ni * 16 + li;
    return ldb8(&Bs[buf][(row << 6) + ((((kh << 2) + lg) ^ sw) << 3)]);
  };

  f32x4 acc[4][NI] = {};

  stage(0, 0);
  __syncthreads();
  int cur = 0;

  for (int k0 = 0; k0 < K; k0 += 64) {
    if (k0 + 64 < K) stage(cur ^ 1, k0 + 64);   // in flight during compute

#pragma unroll
    for (int kh = 0; kh < 2; ++kh) {
      bf16x8 af[4], bfr[NI];
#pragma unroll
      for (int fi = 0; fi < 4; ++fi) af[fi] = ldA(cur, kh, fi);
#pragma unroll
      for (int ni = 0; ni < NI; ++ni) bfr[ni] = ldB(cur, kh, ni);
      __builtin_amdgcn_s_setprio(1);
#pragma unroll
      for (int fi = 0; fi < 4; ++fi)
#pragma unroll
        for (int ni = 0; ni < NI; ++ni)
          acc[fi][ni] = MFMA(af[fi], bfr[ni], acc[fi][ni]);
      __builtin_amdgcn_s_setprio(0);
    }

    __syncthreads();   // drains staging vmcnt + protects buffer reuse
    cur ^= 1;
  }

#pragma unroll
  for (int mi = 0; mi < 4; ++mi) {
#pragma unroll
    for (int ni = 0; ni < NI; ++ni) {
      const int row = brow + wm * 64 + mi * 16 + lg * 4;   // + r
      const int col = bcol + wn * (BN / 4) + ni * 16 + li;
#pragma unroll
      for (int r = 0; r < 4; ++r) {
        const float v = acc[mi][ni][r];
        if (MODE == 0) {
          if (col < 1024) {
            // Q scaled by 1/sqrt(64) * log2(e) for exp2-domain softmax
            Cq[(size_t)(row + r) * 1024 + col] = f2bf(v * 0.18033688f);
          } else if (col < 2048) {
            Ck[(size_t)(row + r) * 1024 + (col - 1024)] = f2bf(v);
          } else {
            const int c = col - 2048;                 // h*64 + d
            const int m = row + r;                    // b*2048 + s
            Cvt[((size_t)c + (size_t)((m >> 11) << 10)) * 2048 + (m & 2047)] = f2bf(v);
          }
        } else {
          Cf[(size_t)(row + r) * 1024 + col] = v + bias[col];
        }
      }
    }
  }
}

// ---------------------------------------------------------------- flash attention
// 4-wave blocks, QBLK=64, KVBLK=64, double-buffered LDS K/V (swizzled).
// CAUSAL PAIRING: each block runs q-tile pr then q-tile 31-pr sequentially
// -> every block does exactly 33 K-tiles (perfect load balance; all 512
// blocks co-resident at 2/CU). XCD head-grouping: 4 heads/XCD (2MB K/V in L2).
// Swapped-operand no-max softmax (exp2 domain, Q pre-scaled by log2e/8).
__global__ __launch_bounds__(256, 3) void attn_fwd(const uint16_t* __restrict__ Q,
                                                   const uint16_t* __restrict__ K,
                                                   const uint16_t* __restrict__ Vt,
                                                   uint16_t* __restrict__ ctx) {
  const int id   = blockIdx.x;
  const int rank = id >> 3;                  // 0..63
  const int bh   = (id & 7) * 4 + (rank >> 4);
  const int pr   = rank & 15;                // pair index 0..15
  const int b = bh >> 4, h = bh & 15;

  const int t  = threadIdx.x;
  const int w  = t >> 6, l = t & 63;
  const int li = l & 15, lg = l >> 4;

  __shared__ uint16_t Kl[2][64 * 64];   // 8KB x2 (key, d), swizzled
  __shared__ uint16_t Vl[2][64 * 64];   // 8KB x2 (d, key), swizzled
  __shared__ uint16_t P[4][16][72];     // per-wave P slab

  const uint16_t* Kg = K + (size_t)(b * 2048) * 1024 + h * 64;
  const uint16_t* Vg = Vt + (size_t)(b * 1024 + h * 64) * 2048;

  // staging: thread t -> row t>>2 span; 256 thr: row = t>>2? No: 64 rows x 8
  // slots needs 512 slots -> each thread does 2 loads per tile (rows split).
  const int srow = t >> 3;                          // 0..31
  const int scol = ((t & 7) * 8) ^ ((srow & 7) * 8);

  auto stage = [&](int buf, int kt2) {
    const int kb2 = kt2 << 6;
    gld_lds16(Kg + (size_t)(kb2 + srow) * 1024 + scol,      &Kl[buf][t * 8]);
    gld_lds16(Kg + (size_t)(kb2 + 32 + srow) * 1024 + scol, &Kl[buf][2048 + t * 8]);
    gld_lds16(Vg + (size_t)srow * 2048 + kb2 + scol,        &Vl[buf][t * 8]);
    gld_lds16(Vg + (size_t)(32 + srow) * 2048 + kb2 + scol, &Vl[buf][2048 + t * 8]);
  };

  const int fsw = (li & 7) * 8;
  int cur = 0;

#pragma unroll 1
  for (int ph = 0; ph < 2; ++ph) {
    const int qbl  = ph ? (31 - pr) : pr;
    const int qrow = (qbl << 6) + (w << 4);
    const uint16_t* qp = Q + (size_t)(b * 2048 + qrow + li) * 1024 + h * 64 + lg * 8;
    const bf16x8 q0 = ldb8(qp);
    const bf16x8 q1 = ldb8(qp + 32);

    f32x4 o[4] = {};                   // O[d = dt*16 + lg*4 + r][q = li]
    float l_r = 0.f;

    stage(cur, 0);
    __syncthreads();

    for (int kt = 0; kt <= qbl; ++kt) {
      if (kt < qbl) stage(cur ^ 1, kt + 1);

      const uint16_t* Kc = &Kl[cur][0];
      const uint16_t* Vc = &Vl[cur][0];

      // QK^T swapped: s[tt][r] = S[key = kt*64+tt*16+lg*4+r][q = qrow+li]
      f32x4 s[4];
      __builtin_amdgcn_s_setprio(1);
#pragma unroll
      for (int tt = 0; tt < 4; ++tt) {
        const uint16_t* kr = Kc + (tt * 16 + li) * 64;
        f32x4 z = {};
        z = MFMA(ldb8(kr + ((lg * 8) ^ fsw)), q0, z);
        z = MFMA(ldb8(kr + ((32 + lg * 8) ^ fsw)), q1, z);
        s[tt] = z;
      }
      __builtin_amdgcn_s_setprio(0);

      // V fragments: lane holds V[d = dt*16 + li][key = half*32 + lg*8 + j]
      bf16x8 vf[4][2];
#pragma unroll
      for (int dt = 0; dt < 4; ++dt) {
        const uint16_t* vr = Vc + (dt * 16 + li) * 64;
        vf[dt][0] = ldb8(vr + ((lg * 8) ^ fsw));
        vf[dt][1] = ldb8(vr + ((32 + lg * 8) ^ fsw));
      }

      if (kt == qbl) {   // diagonal tile: causal mask -> exp2 gives exact 0
        const int qloc = (w << 4) + li;
#pragma unroll
        for (int tt = 0; tt < 4; ++tt) {
          const int key = (tt << 4) + (lg << 2);
#pragma unroll
          for (int r = 0; r < 4; ++r)
            if (key + r > qloc) s[tt][r] = -1e30f;
        }
      }

      // ---- no-max softmax: P = exp2(s), per-lane partial l
      float lsum = 0.f;
      ushort4 pk[4];
#pragma unroll
      for (int tt = 0; tt < 4; ++tt) {
        f32x4 p;
        p[0] = __builtin_amdgcn_exp2f(s[tt][0]);
        p[1] = __builtin_amdgcn_exp2f(s[tt][1]);
        p[2] = __builtin_amdgcn_exp2f(s[tt][2]);
        p[3] = __builtin_amdgcn_exp2f(s[tt][3]);
        lsum += (p[0] + p[1]) + (p[2] + p[3]);
        pk[tt] = pack4(p);
      }
      l_r += lsum;

      // ---- P relayout via per-wave LDS slab
#pragma unroll
      for (int tt = 0; tt < 4; ++tt)
        *(ushort4*)&P[w][li][(tt << 4) + (lg << 2)] = pk[tt];
      asm volatile("s_waitcnt lgkmcnt(0)" ::: "memory");

      const bf16x8 pb0 = ldb8(&P[w][li][lg * 8]);
      const bf16x8 pb1 = ldb8(&P[w][li][32 + lg * 8]);
      __builtin_amdgcn_s_setprio(1);
#pragma unroll
      for (int dt = 0; dt < 4; ++dt) {
        o[dt] = MFMA(vf[dt][0], pb0, o[dt]);
        o[dt] = MFMA(vf[dt][1], pb1, o[dt]);
      }
      __builtin_amdgcn_s_setprio(0);

      __syncthreads();
      cur ^= 1;
    }

    // final l reduce across the 4 lg-groups sharing q = li
    l_r += __shfl_xor(l_r, 16);
    l_r += __shfl_xor(l_r, 32);
    const float inv = 1.0f / l_r;
    const int qg = b * 2048 + qrow + li;
#pragma unroll
    for (int dt = 0; dt < 4; ++dt) {
      f32x4 ov = o[dt];
      ov[0] *= inv; ov[1] *= inv; ov[2] *= inv; ov[3] *= inv;
      *(ushort4*)(ctx + (size_t)qg * 1024 + h * 64 + (dt << 4) + (lg << 2)) = pack4(ov);
    }
  }
}

// ---------------------------------------------------------------- launch
extern "C" void kernel_launch(void* const* d_in, const int* in_sizes, int n_in,
                              void* d_out, int out_size, void* d_ws, size_t ws_size,
                              hipStream_t stream) {
  const float* x  = (const float*)d_in[0];
  const float* Wq = (const float*)d_in[1];
  const float* Wk = (const float*)d_in[2];
  const float* Wv = (const float*)d_in[3];
  const float* Wo = (const float*)d_in[4];
  const float* bo = (const float*)d_in[5];
  float* out = (float*)d_out;

  char* ws = (char*)d_ws;
  uint16_t* xb   = (uint16_t*)(ws);                 // 8MB (dead after QKV gemm)
  uint16_t* Wqkv = (uint16_t*)(ws + ( 8u << 20));   // 6MB: Wq|Wk|Wv contiguous
  uint16_t* Wob  = (uint16_t*)(ws + (14u << 20));   // 2MB
  uint16_t* Qb   = (uint16_t*)(ws + (16u << 20));   // 8MB
  uint16_t* Kb   = (uint16_t*)(ws + (24u << 20));   // 8MB
  uint16_t* Vt   = (uint16_t*)(ws + (32u << 20));   // 8MB
  uint16_t* Ctx  = (uint16_t*)(ws);                 // overlays xb

  cvt_all<<<8192, 256, 0, stream>>>(x, Wq, Wk, Wv, Wo, xb, Wqkv, Wob);

  // fused QKV projection: 128x192 tiles, 512 thr, grid 16x32 (=2/CU exactly)
  gemm_bt<0><<<dim3(16, 32), 512, 0, stream>>>(xb, Wqkv, Qb, Kb, Vt,
                                               nullptr, nullptr);

  // attention: 512 blocks (XCD-mapped, causal-paired), 4 waves
  attn_fwd<<<512, 256, 0, stream>>>(Qb, Kb, Vt, Ctx);

  // output projection + bias: 128x64 tiles, 512 thr, grid 16x32
  gemm_bt<2><<<dim3(16, 32), 512, 0, stream>>>(Ctx, Wob, nullptr, nullptr, nullptr,
                                               out, bo);
}

// Round 10
// 99.124 us; speedup vs baseline: 1.2386x; 1.0991x over previous
//
#include <hip/hip_runtime.h>
#include <stdint.h>

#define SEQ   2048
#define DEMB  1024
#define NH    16
#define HD    64
#define MROWS 4096   // BS*SEQ

typedef __bf16 bf16x8 __attribute__((ext_vector_type(8)));
typedef __bf16 bf16x4 __attribute__((ext_vector_type(4)));
typedef float  f32x4  __attribute__((ext_vector_type(4)));

#define MFMA(a, b, c) __builtin_amdgcn_mfma_f32_16x16x32_bf16((a), (b), (c), 0, 0, 0)

static __device__ __forceinline__ uint16_t f2bf(float f) {
  union { __bf16 b; uint16_t u; } c;
  c.b = (__bf16)f;
  return c.u;
}

static __device__ __forceinline__ ushort4 pack4(f32x4 f) {
  union { bf16x4 b; ushort4 u; } c;
  c.b[0] = (__bf16)f[0]; c.b[1] = (__bf16)f[1];
  c.b[2] = (__bf16)f[2]; c.b[3] = (__bf16)f[3];
  return c.u;
}

static __device__ __forceinline__ bf16x8 ldb8(const uint16_t* p) {
  union { uint4 i; bf16x8 b; } u;
  u.i = *(const uint4*)p;
  return u.b;
}

static __device__ __forceinline__ void gld_lds16(const uint16_t* g, uint16_t* l) {
  __builtin_amdgcn_global_load_lds(
      (const __attribute__((address_space(1))) uint32_t*)(g),
      (__attribute__((address_space(3))) uint32_t*)(l),
      16, 0, 0);
}

// ---------------------------------------------------------------- fused converts
__global__ __launch_bounds__(256) void cvt_all(const float* __restrict__ x,
                                               const float* __restrict__ wq,
                                               const float* __restrict__ wk,
                                               const float* __restrict__ wv,
                                               const float* __restrict__ wo,
                                               uint16_t* __restrict__ xb,
                                               uint16_t* __restrict__ wqkv,
                                               uint16_t* __restrict__ wob) {
  const int bid = blockIdx.x;
  const float* src; uint16_t* dst; int off;
  if (bid < 4096)      { src = x;  dst = xb;                 off = bid; }
  else if (bid < 5120) { src = wq; dst = wqkv;               off = bid - 4096; }
  else if (bid < 6144) { src = wk; dst = wqkv + (1u << 20);  off = bid - 5120; }
  else if (bid < 7168) { src = wv; dst = wqkv + (2u << 20);  off = bid - 6144; }
  else                 { src = wo; dst = wob;                off = bid - 7168; }
  const int i = (off * 256 + threadIdx.x) * 4;
  float4 v = *(const float4*)(src + i);
  f32x4 f; f[0] = v.x; f[1] = v.y; f[2] = v.z; f[3] = v.w;
  *(ushort4*)(dst + i) = pack4(f);
}

// ---------------------------------------------------------------- QKV GEMM
// C = A(4096x1024) * B(3072x1024)^T. Tile 256x192, BK=64, 512 thr (8 waves
// 2Mx4N, wave-tile 128x48 -> 70 FLOP per LDS-read-byte vs R8's 55).
// Grid 16x16 = 256 blocks = exactly 1/CU, uniform. 112 KB LDS double-buffered,
// conflict-free XOR swizzle (R5/R7-validated: 0 conflicts).
// LDS layout (u16 elems): As buf0 @0, As buf1 @16384, Bs buf0 @32768,
// Bs buf1 @45056. NOTE: no arrays of LDS pointers (addrspacecast static-init
// is unsupported, R9 compile failure) -- offsets computed inline from base.
// Epilogue: [0,1024)->Q (*log2e/8), [1024,2048)->K, [2048,3072)->V^T written
// COALESCED via per-wave LDS transpose slab (reuses staging LDS).
__global__ __launch_bounds__(512, 2) void gemm_qkv(const uint16_t* __restrict__ A,
                                                   const uint16_t* __restrict__ B,
                                                   uint16_t* __restrict__ Cq,
                                                   uint16_t* __restrict__ Ck,
                                                   uint16_t* __restrict__ Cvt) {
  constexpr int K = 1024;
  __shared__ uint16_t lds[57344];      // 112 KB

  const int bcol = blockIdx.x * 192;   // x-major: XCD keeps 2 B-panels resident
  const int brow = blockIdx.y << 8;

  const int t  = threadIdx.x;
  const int l  = t & 63;
  const int li = l & 15, lg = l >> 4;
  const int w  = t >> 6;               // 0..7
  const int wm = w >> 2;               // row half: wm*128
  const int wn = w & 3;                // col quarter: wn*48

  // staging: thread t -> row t>>3 (0..63 per call), 16B-slot t&7; source col
  // pre-swizzled by (row&7); linear LDS dest + XOR reads = 0 conflicts.
  const int srow = t >> 3;
  const int scol = ((t & 7) ^ (srow & 7)) << 3;
  const uint16_t* gA = A + (size_t)(brow + srow) * K + scol;
  const uint16_t* gB = B + (size_t)(bcol + srow) * K + scol;

  auto stage = [&](int buf, int k0) {
    uint16_t* as = lds + buf * 16384;
    uint16_t* bs = lds + 32768 + buf * 12288;
    gld_lds16(gA + k0,                    as + t * 8);
    gld_lds16(gA + (size_t)64 * K + k0,   as + 4096 + t * 8);
    gld_lds16(gA + (size_t)128 * K + k0,  as + 8192 + t * 8);
    gld_lds16(gA + (size_t)192 * K + k0,  as + 12288 + t * 8);
    gld_lds16(gB + k0,                    bs + t * 8);
    gld_lds16(gB + (size_t)64 * K + k0,   bs + 4096 + t * 8);
    gld_lds16(gB + (size_t)128 * K + k0,  bs + 8192 + t * 8);
  };

  const int sw = li & 7;               // fragment-read swizzle
  auto ldA = [&](int buf, int kh, int fi) {
    const int row = wm * 128 + fi * 16 + li;
    return ldb8(&lds[buf * 16384 + (row << 6) + ((((kh << 2) + lg) ^ sw) << 3)]);
  };
  auto ldB = [&](int buf, int kh, int ni) {
    const int row = wn * 48 + ni * 16 + li;
    return ldb8(&lds[32768 + buf * 12288 + (row << 6) + ((((kh << 2) + lg) ^ sw) << 3)]);
  };

  f32x4 acc[8][3] = {};

  stage(0, 0);
  __syncthreads();
  int cur = 0;

  for (int k0 = 0; k0 < K; k0 += 64) {
    if (k0 + 64 < K) stage(cur ^ 1, k0 + 64);   // in flight during compute

#pragma unroll
    for (int kh = 0; kh < 2; ++kh) {
      bf16x8 af[8], bfr[3];
#pragma unroll
      for (int ni = 0; ni < 3; ++ni) bfr[ni] = ldB(cur, kh, ni);
#pragma unroll
      for (int fi = 0; fi < 8; ++fi) af[fi] = ldA(cur, kh, fi);
      __builtin_amdgcn_s_setprio(1);
#pragma unroll
      for (int fi = 0; fi < 8; ++fi)
#pragma unroll
        for (int ni = 0; ni < 3; ++ni)
          acc[fi][ni] = MFMA(af[fi], bfr[ni], acc[fi][ni]);
      __builtin_amdgcn_s_setprio(0);
    }

    __syncthreads();   // drains staging vmcnt + protects buffer reuse
    cur ^= 1;
  }

  // ---- epilogue. Q/K: direct stores. V: per-wave LDS transpose -> coalesced.
  // slab: per-wave 48 c-rows x 136 elems (272B stride: 2-way-max bank aliasing)
  uint16_t* slab = lds + w * 6800;
  bool anyV = false;

#pragma unroll
  for (int mi = 0; mi < 8; ++mi) {
#pragma unroll
    for (int ni = 0; ni < 3; ++ni) {
      const int col = bcol + wn * 48 + ni * 16 + li;
      const int row = brow + wm * 128 + mi * 16 + lg * 4;   // + r
      if (col < 1024) {
#pragma unroll
        for (int r = 0; r < 4; ++r)
          Cq[(size_t)(row + r) * 1024 + col] = f2bf(acc[mi][ni][r] * 0.18033688f);
      } else if (col < 2048) {
#pragma unroll
        for (int r = 0; r < 4; ++r)
          Ck[(size_t)(row + r) * 1024 + (col - 1024)] = f2bf(acc[mi][ni][r]);
      } else {
        anyV = true;
        // transposed slab write: c_loc = ni*16+li, 4 consecutive m packed as 8B
        *(ushort4*)&slab[(ni * 16 + li) * 136 + mi * 16 + lg * 4] = pack4(acc[mi][ni]);
      }
    }
  }

  if (anyV) {
    asm volatile("s_waitcnt lgkmcnt(0)" ::: "memory");
    const int m0 = brow + wm * 128;           // 128 consecutive m, same batch
    const size_t mbase = (size_t)((m0 >> 11) << 10) * 2048 + (m0 & 2047);
#pragma unroll
    for (int cc = 0; cc < 12; ++cc) {
      const int c_loc = cc * 4 + lg;
      const int cglob = bcol + wn * 48 + c_loc;
      if (cglob >= 2048) {
        const int c = cglob - 2048;           // h*64 + d
        uint4 v = *(const uint4*)&slab[c_loc * 136 + li * 8];
        *(uint4*)(Cvt + (size_t)c * 2048 + mbase + li * 8) = v;
      }
    }
  }
}

// ---------------------------------------------------------------- out projection
// Tile 128x128, BK=64, 512 thr (8 waves 2Mx4N, wave-tile 64x32), grid 8x32 =
// 256 blocks = 1/CU uniform. fp32 out + bias.
__global__ __launch_bounds__(512, 2) void gemm_out(const uint16_t* __restrict__ A,
                                                   const uint16_t* __restrict__ B,
                                                   float* __restrict__ Cf,
                                                   const float* __restrict__ bias) {
  constexpr int K = 1024;
  __shared__ uint16_t As[2][128 * 64];   // 32 KB
  __shared__ uint16_t Bs[2][128 * 64];   // 32 KB

  const int bcol = blockIdx.x << 7;
  const int brow = blockIdx.y << 7;

  const int t  = threadIdx.x;
  const int l  = t & 63;
  const int li = l & 15, lg = l >> 4;
  const int w  = t >> 6;
  const int wm = w >> 2;               // row half: wm*64
  const int wn = w & 3;                // col quarter: wn*32

  const int srow = t >> 3;
  const int scol = ((t & 7) ^ (srow & 7)) << 3;
  const uint16_t* gA = A + (size_t)(brow + srow) * K + scol;
  const uint16_t* gB = B + (size_t)(bcol + srow) * K + scol;

  auto stage = [&](int buf, int k0) {
    gld_lds16(gA + k0,                  &As[buf][t * 8]);
    gld_lds16(gA + (size_t)64 * K + k0, &As[buf][4096 + t * 8]);
    gld_lds16(gB + k0,                  &Bs[buf][t * 8]);
    gld_lds16(gB + (size_t)64 * K + k0, &Bs[buf][4096 + t * 8]);
  };

  const int sw = li & 7;
  auto ldA = [&](int buf, int kh, int fi) {
    const int row = wm * 64 + fi * 16 + li;
    return ldb8(&As[buf][(row << 6) + ((((kh << 2) + lg) ^ sw) << 3)]);
  };
  auto ldB = [&](int buf, int kh, int ni) {
    const int row = wn * 32 + ni * 16 + li;
    return ldb8(&Bs[buf][(row << 6) + ((((kh << 2) + lg) ^ sw) << 3)]);
  };

  f32x4 acc[4][2] = {};

  stage(0, 0);
  __syncthreads();
  int cur = 0;

  for (int k0 = 0; k0 < K; k0 += 64) {
    if (k0 + 64 < K) stage(cur ^ 1, k0 + 64);

#pragma unroll
    for (int kh = 0; kh < 2; ++kh) {
      bf16x8 af[4], bfr[2];
#pragma unroll
      for (int ni = 0; ni < 2; ++ni) bfr[ni] = ldB(cur, kh, ni);
#pragma unroll
      for (int fi = 0; fi < 4; ++fi) af[fi] = ldA(cur, kh, fi);
      __builtin_amdgcn_s_setprio(1);
#pragma unroll
      for (int fi = 0; fi < 4; ++fi)
#pragma unroll
        for (int ni = 0; ni < 2; ++ni)
          acc[fi][ni] = MFMA(af[fi], bfr[ni], acc[fi][ni]);
      __builtin_amdgcn_s_setprio(0);
    }

    __syncthreads();
    cur ^= 1;
  }

#pragma unroll
  for (int mi = 0; mi < 4; ++mi) {
#pragma unroll
    for (int ni = 0; ni < 2; ++ni) {
      const int row = brow + wm * 64 + mi * 16 + lg * 4;
      const int col = bcol + wn * 32 + ni * 16 + li;
      const float bv = bias[col];
#pragma unroll
      for (int r = 0; r < 4; ++r)
        Cf[(size_t)(row + r) * 1024 + col] = acc[mi][ni][r] + bv;
    }
  }
}

// ---------------------------------------------------------------- flash attention
// (unchanged from R8: 4-wave, causal-paired, XCD head-grouped, no-max softmax)
__global__ __launch_bounds__(256, 3) void attn_fwd(const uint16_t* __restrict__ Q,
                                                   const uint16_t* __restrict__ K,
                                                   const uint16_t* __restrict__ Vt,
                                                   uint16_t* __restrict__ ctx) {
  const int id   = blockIdx.x;
  const int rank = id >> 3;                  // 0..63
  const int bh   = (id & 7) * 4 + (rank >> 4);
  const int pr   = rank & 15;                // pair index 0..15
  const int b = bh >> 4, h = bh & 15;

  const int t  = threadIdx.x;
  const int w  = t >> 6, l = t & 63;
  const int li = l & 15, lg = l >> 4;

  __shared__ uint16_t Kl[2][64 * 64];
  __shared__ uint16_t Vl[2][64 * 64];
  __shared__ uint16_t P[4][16][72];

  const uint16_t* Kg = K + (size_t)(b * 2048) * 1024 + h * 64;
  const uint16_t* Vg = Vt + (size_t)(b * 1024 + h * 64) * 2048;

  const int srow = t >> 3;                          // 0..31
  const int scol = ((t & 7) * 8) ^ ((srow & 7) * 8);

  auto stage = [&](int buf, int kt2) {
    const int kb2 = kt2 << 6;
    gld_lds16(Kg + (size_t)(kb2 + srow) * 1024 + scol,      &Kl[buf][t * 8]);
    gld_lds16(Kg + (size_t)(kb2 + 32 + srow) * 1024 + scol, &Kl[buf][2048 + t * 8]);
    gld_lds16(Vg + (size_t)srow * 2048 + kb2 + scol,        &Vl[buf][t * 8]);
    gld_lds16(Vg + (size_t)(32 + srow) * 2048 + kb2 + scol, &Vl[buf][2048 + t * 8]);
  };

  const int fsw = (li & 7) * 8;
  int cur = 0;

#pragma unroll 1
  for (int ph = 0; ph < 2; ++ph) {
    const int qbl  = ph ? (31 - pr) : pr;
    const int qrow = (qbl << 6) + (w << 4);
    const uint16_t* qp = Q + (size_t)(b * 2048 + qrow + li) * 1024 + h * 64 + lg * 8;
    const bf16x8 q0 = ldb8(qp);
    const bf16x8 q1 = ldb8(qp + 32);

    f32x4 o[4] = {};
    float l_r = 0.f;

    stage(cur, 0);
    __syncthreads();

    for (int kt = 0; kt <= qbl; ++kt) {
      if (kt < qbl) stage(cur ^ 1, kt + 1);

      const uint16_t* Kc = &Kl[cur][0];
      const uint16_t* Vc = &Vl[cur][0];

      f32x4 s[4];
      __builtin_amdgcn_s_setprio(1);
#pragma unroll
      for (int tt = 0; tt < 4; ++tt) {
        const uint16_t* kr = Kc + (tt * 16 + li) * 64;
        f32x4 z = {};
        z = MFMA(ldb8(kr + ((lg * 8) ^ fsw)), q0, z);
        z = MFMA(ldb8(kr + ((32 + lg * 8) ^ fsw)), q1, z);
        s[tt] = z;
      }
      __builtin_amdgcn_s_setprio(0);

      bf16x8 vf[4][2];
#pragma unroll
      for (int dt = 0; dt < 4; ++dt) {
        const uint16_t* vr = Vc + (dt * 16 + li) * 64;
        vf[dt][0] = ldb8(vr + ((lg * 8) ^ fsw));
        vf[dt][1] = ldb8(vr + ((32 + lg * 8) ^ fsw));
      }

      if (kt == qbl) {
        const int qloc = (w << 4) + li;
#pragma unroll
        for (int tt = 0; tt < 4; ++tt) {
          const int key = (tt << 4) + (lg << 2);
#pragma unroll
          for (int r = 0; r < 4; ++r)
            if (key + r > qloc) s[tt][r] = -1e30f;
        }
      }

      float lsum = 0.f;
      ushort4 pk[4];
#pragma unroll
      for (int tt = 0; tt < 4; ++tt) {
        f32x4 p;
        p[0] = __builtin_amdgcn_exp2f(s[tt][0]);
        p[1] = __builtin_amdgcn_exp2f(s[tt][1]);
        p[2] = __builtin_amdgcn_exp2f(s[tt][2]);
        p[3] = __builtin_amdgcn_exp2f(s[tt][3]);
        lsum += (p[0] + p[1]) + (p[2] + p[3]);
        pk[tt] = pack4(p);
      }
      l_r += lsum;

#pragma unroll
      for (int tt = 0; tt < 4; ++tt)
        *(ushort4*)&P[w][li][(tt << 4) + (lg << 2)] = pk[tt];
      asm volatile("s_waitcnt lgkmcnt(0)" ::: "memory");

      const bf16x8 pb0 = ldb8(&P[w][li][lg * 8]);
      const bf16x8 pb1 = ldb8(&P[w][li][32 + lg * 8]);
      __builtin_amdgcn_s_setprio(1);
#pragma unroll
      for (int dt = 0; dt < 4; ++dt) {
        o[dt] = MFMA(vf[dt][0], pb0, o[dt]);
        o[dt] = MFMA(vf[dt][1], pb1, o[dt]);
      }
      __builtin_amdgcn_s_setprio(0);

      __syncthreads();
      cur ^= 1;
    }

    l_r += __shfl_xor(l_r, 16);
    l_r += __shfl_xor(l_r, 32);
    const float inv = 1.0f / l_r;
    const int qg = b * 2048 + qrow + li;
#pragma unroll
    for (int dt = 0; dt < 4; ++dt) {
      f32x4 ov = o[dt];
      ov[0] *= inv; ov[1] *= inv; ov[2] *= inv; ov[3] *= inv;
      *(ushort4*)(ctx + (size_t)qg * 1024 + h * 64 + (dt << 4) + (lg << 2)) = pack4(ov);
    }
  }
}

// ---------------------------------------------------------------- launch
extern "C" void kernel_launch(void* const* d_in, const int* in_sizes, int n_in,
                              void* d_out, int out_size, void* d_ws, size_t ws_size,
                              hipStream_t stream) {
  const float* x  = (const float*)d_in[0];
  const float* Wq = (const float*)d_in[1];
  const float* Wk = (const float*)d_in[2];
  const float* Wv = (const float*)d_in[3];
  const float* Wo = (const float*)d_in[4];
  const float* bo = (const float*)d_in[5];
  float* out = (float*)d_out;

  char* ws = (char*)d_ws;
  uint16_t* xb   = (uint16_t*)(ws);                 // 8MB (dead after QKV gemm)
  uint16_t* Wqkv = (uint16_t*)(ws + ( 8u << 20));   // 6MB: Wq|Wk|Wv contiguous
  uint16_t* Wob  = (uint16_t*)(ws + (14u << 20));   // 2MB
  uint16_t* Qb   = (uint16_t*)(ws + (16u << 20));   // 8MB
  uint16_t* Kb   = (uint16_t*)(ws + (24u << 20));   // 8MB
  uint16_t* Vt   = (uint16_t*)(ws + (32u << 20));   // 8MB
  uint16_t* Ctx  = (uint16_t*)(ws);                 // overlays xb

  cvt_all<<<8192, 256, 0, stream>>>(x, Wq, Wk, Wv, Wo, xb, Wqkv, Wob);

  // fused QKV projection: 256x192 tiles, grid 16x16 = 256 blocks (1/CU)
  gemm_qkv<<<dim3(16, 16), 512, 0, stream>>>(xb, Wqkv, Qb, Kb, Vt);

  // attention: 512 blocks (XCD-mapped, causal-paired), 4 waves
  attn_fwd<<<512, 256, 0, stream>>>(Qb, Kb, Vt, Ctx);

  // output projection + bias: 128x128 tiles, grid 8x32 = 256 blocks (1/CU)
  gemm_out<<<dim3(8, 32), 512, 0, stream>>>(Ctx, Wob, out, bo);
}